// Round 1
// baseline (1060.206 us; speedup 1.0000x reference)
//
#include <hip/hip_runtime.h>
#include <stdint.h>

// ---------------------------------------------------------------------------
// KnowledgeCircuit: B=4 S=2048 D=1024 N=64 R=128, M = B*S = 8192 tokens.
// Stage 1: h[m,r]   = sum_{n,d} (w1[m,n]*x[m,d]) * F[n*1024+d, r]   (K=65536)
// Stage 2: out[m,d] = sum_{n,r} (w2[m,n]*h[m,r]) * Rk[n*128+r, d]   (K=8192)
// Both are GEMMs with on-the-fly A = weight[m, k>>SHIFT] * base[m, k&MASK].
// ---------------------------------------------------------------------------

typedef __attribute__((ext_vector_type(8))) short frag_t;   // 8 bf16 (4 VGPRs)
typedef __attribute__((ext_vector_type(4))) float f32x4;

#define TM 128
#define TN 128
#define BK 32
#define PAD 40   // LDS row stride (bf16 elems): 80B rows, 16B aligned, conflict-free frag reads

__device__ __forceinline__ unsigned short f2bf(float f) {
    unsigned int u = __builtin_bit_cast(unsigned int, f);
    u = (u + 0x7FFFu + ((u >> 16) & 1u)) >> 16;   // round-to-nearest-even
    return (unsigned short)u;
}

template<int INNER_SHIFT, bool ATOMIC>
__global__ __launch_bounds__(256, 2)
void kc_gemm(const float* __restrict__ Abase,   // M x (1<<INNER_SHIFT) base matrix (x or h)
             const float* __restrict__ W,       // M x 64 weights (w1 or w2)
             const float* __restrict__ Bmat,    // K x ldB (feature_know / restore_know flat)
             float* __restrict__ C,             // M x ldC output (h or out)
             int ldA, int ldB, int ldC, int ksteps)
{
    __shared__ unsigned short As[TM * PAD];   // As[m][k], k in [0,32)
    __shared__ unsigned short Bs[TN * PAD];   // Bs[n][k] (transposed in staging)

    const int t  = threadIdx.x;
    const int m0 = blockIdx.x * TM;
    const int n0 = blockIdx.y * TN;
    const int kbase = blockIdx.z * ksteps * BK;

    // A staging: thread -> (4 cols via float4, 32 rows strided by 32)
    const int ad = 4 * (t & 7);
    const int am = t >> 3;              // 0..31
    // B staging: thread -> 2 adjacent cols (n), 8 k-rows
    const int bn = 2 * (t & 63);        // 0..126
    const int bk = (t >> 6) * 8;        // 0,8,16,24

    const int lane = t & 63;
    const int wv   = t >> 6;
    const int wm   = (wv & 1) * 64;
    const int wn   = (wv >> 1) * 64;
    const int fr   = lane & 15;
    const int fk   = (lane >> 4) * 8;

    f32x4 acc[4][4];
    #pragma unroll
    for (int i = 0; i < 4; ++i)
        #pragma unroll
        for (int j = 0; j < 4; ++j)
            acc[i][j] = (f32x4){0.f, 0.f, 0.f, 0.f};

    for (int ks = 0; ks < ksteps; ++ks) {
        const int k0   = kbase + ks * BK;
        const int nidx = k0 >> INNER_SHIFT;
        const int d0   = k0 & ((1 << INNER_SHIFT) - 1);

        __syncthreads();   // previous iteration's frag reads done

        // ---- stage A: As[m][k] = bf16( W[m0+m, nidx] * Abase[m0+m, d0+k] )
        #pragma unroll
        for (int p = 0; p < 4; ++p) {
            const int m = am + 32 * p;
            const float w = W[(size_t)(m0 + m) * 64 + nidx];
            const float4 v = *(const float4*)(Abase + (size_t)(m0 + m) * ldA + d0 + ad);
            unsigned int p0 = (unsigned int)f2bf(v.x * w) | ((unsigned int)f2bf(v.y * w) << 16);
            unsigned int p1 = (unsigned int)f2bf(v.z * w) | ((unsigned int)f2bf(v.w * w) << 16);
            *(uint2*)&As[m * PAD + ad] = make_uint2(p0, p1);
        }

        // ---- stage B (transpose): Bs[n][k] = bf16( Bmat[k0+k, n0+n] )
        unsigned int pa[4], pb[4];
        #pragma unroll
        for (int jj = 0; jj < 4; ++jj) {
            const float2 v0 = *(const float2*)(Bmat + (size_t)(k0 + bk + 2*jj)     * ldB + n0 + bn);
            const float2 v1 = *(const float2*)(Bmat + (size_t)(k0 + bk + 2*jj + 1) * ldB + n0 + bn);
            pa[jj] = (unsigned int)f2bf(v0.x) | ((unsigned int)f2bf(v1.x) << 16);
            pb[jj] = (unsigned int)f2bf(v0.y) | ((unsigned int)f2bf(v1.y) << 16);
        }
        *(uint4*)&Bs[bn * PAD + bk]       = make_uint4(pa[0], pa[1], pa[2], pa[3]);
        *(uint4*)&Bs[(bn + 1) * PAD + bk] = make_uint4(pb[0], pb[1], pb[2], pb[3]);

        __syncthreads();

        // ---- compute: 16 MFMAs per wave per K-step
        frag_t a[4], b[4];
        #pragma unroll
        for (int i = 0; i < 4; ++i)
            a[i] = *reinterpret_cast<const frag_t*>(&As[(wm + 16*i + fr) * PAD + fk]);
        #pragma unroll
        for (int j = 0; j < 4; ++j)
            b[j] = *reinterpret_cast<const frag_t*>(&Bs[(wn + 16*j + fr) * PAD + fk]);
        #pragma unroll
        for (int i = 0; i < 4; ++i)
            #pragma unroll
            for (int j = 0; j < 4; ++j)
                acc[i][j] = __builtin_amdgcn_mfma_f32_16x16x32_bf16(a[i], b[j], acc[i][j], 0, 0, 0);
    }

    // ---- epilogue: C/D layout col=lane&15, row=(lane>>4)*4+reg
    const int row4 = (lane >> 4) * 4;
    const int col  = lane & 15;
    #pragma unroll
    for (int i = 0; i < 4; ++i) {
        #pragma unroll
        for (int j = 0; j < 4; ++j) {
            #pragma unroll
            for (int r = 0; r < 4; ++r) {
                const int gm = m0 + wm + 16*i + row4 + r;
                const int gn = n0 + wn + 16*j + col;
                const float v = acc[i][j][r];
                if constexpr (ATOMIC)
                    atomicAdd(&C[(size_t)gm * ldC + gn], v);
                else
                    C[(size_t)gm * ldC + gn] = v;
            }
        }
    }
}

extern "C" void kernel_launch(void* const* d_in, const int* in_sizes, int n_in,
                              void* d_out, int out_size, void* d_ws, size_t ws_size,
                              hipStream_t stream) {
    const float* x  = (const float*)d_in[0];   // [8192, 1024]
    const float* w1 = (const float*)d_in[1];   // [8192, 64]
    const float* w2 = (const float*)d_in[2];   // [8192, 64]
    const float* F  = (const float*)d_in[3];   // [64, 1024, 128] -> (65536, 128)
    const float* Rk = (const float*)d_in[4];   // [64, 128, 1024] -> (8192, 1024)
    float* out = (float*)d_out;                // [8192, 1024]
    float* h   = (float*)d_ws;                 // [8192, 128] fp32 scratch (4 MB)

    // zero h (ws is poisoned 0xAA before every launch)
    hipMemsetAsync(h, 0, (size_t)8192 * 128 * sizeof(float), stream);

    dim3 blk(256);

    // Stage 1: M=8192 K=65536 N=128, split-K over 8 chunks (8 n-values each)
    dim3 g1(64, 1, 8);
    kc_gemm<10, true><<<g1, blk, 0, stream>>>(x, w1, F, h, 1024, 128, 128, 256);

    // Stage 2: M=8192 K=8192 N=1024
    dim3 g2(64, 8, 1);
    kc_gemm<7, false><<<g2, blk, 0, stream>>>(h, w2, Rk, out, 128, 1024, 1024, 256);
}

// Round 2
// 497.035 us; speedup vs baseline: 2.1331x; 2.1331x over previous
//
#include <hip/hip_runtime.h>
#include <stdint.h>

// ---------------------------------------------------------------------------
// KnowledgeCircuit: B=4 S=2048 D=1024 N=64 R=128, M = B*S = 8192 tokens.
// Stage 1: h[m,r]   = sum_n w1[m,n] * (sum_d x[m,d] F[n,d,r])     K=65536
// Stage 2: out[m,d] = sum_n w2[m,n] * (sum_r h[m,r] Rk[n,r,d])    K=8192
// m97-structure GEMM: bf16 prepass + global_load_lds dwordx4 staging +
// XOR-swizzled LDS + weight scale deferred to per-segment accumulator fold.
// ---------------------------------------------------------------------------

typedef unsigned short ushort_t;
typedef __attribute__((ext_vector_type(8))) short frag_t;   // 8 bf16
typedef __attribute__((ext_vector_type(4))) float f32x4;

#define BK 128

__device__ __forceinline__ unsigned short f2bf(float f) {
    unsigned int u = __builtin_bit_cast(unsigned int, f);
    u = (u + 0x7FFFu + ((u >> 16) & 1u)) >> 16;   // RTNE
    return (unsigned short)u;
}

__device__ __forceinline__ void glds16(const ushort_t* g, ushort_t* l) {
    __builtin_amdgcn_global_load_lds(
        (const __attribute__((address_space(1))) unsigned int*)g,
        (__attribute__((address_space(3))) unsigned int*)l,
        16, 0, 0);
}

// ---------------- prepass: fp32 -> bf16 elementwise -------------------------
__global__ __launch_bounds__(256) void convert_bf(const float* __restrict__ in,
                                                  ushort_t* __restrict__ out, int n8) {
    int idx = blockIdx.x * 256 + threadIdx.x;
    if (idx >= n8) return;
    const float4 v0 = ((const float4*)in)[idx * 2];
    const float4 v1 = ((const float4*)in)[idx * 2 + 1];
    unsigned short b[8] = { f2bf(v0.x), f2bf(v0.y), f2bf(v0.z), f2bf(v0.w),
                            f2bf(v1.x), f2bf(v1.y), f2bf(v1.z), f2bf(v1.w) };
    ((uint4*)out)[idx] = *(const uint4*)b;
}

// ---------------- prepass: fp32 RxC -> bf16 CxR transpose -------------------
__global__ __launch_bounds__(256) void transpose_bf(const float* __restrict__ in,
                                                    ushort_t* __restrict__ out,
                                                    int R, int C) {
    __shared__ float tile[64][65];
    const int t  = threadIdx.x;
    const int r0 = blockIdx.x * 64;
    const int c0 = blockIdx.y * 64;
    const int ci = t & 63;
    const int rb = t >> 6;
    #pragma unroll
    for (int p = 0; p < 16; ++p)
        tile[rb + 4 * p][ci] = in[(size_t)(r0 + rb + 4 * p) * C + c0 + ci];
    __syncthreads();
    const int cw = t >> 2;          // 0..63 output row (input col)
    const int rg = (t & 3) * 16;    // 16 consecutive r per thread
    unsigned short buf[16];
    #pragma unroll
    for (int k = 0; k < 16; ++k)
        buf[k] = f2bf(tile[rg + k][cw]);
    uint4* dst = (uint4*)&out[(size_t)(c0 + cw) * R + r0 + rg];
    dst[0] = *(const uint4*)&buf[0];
    dst[1] = *(const uint4*)&buf[8];
}

// ---------------- main GEMM -------------------------------------------------
// A[m,k] = W[m, k>>SHIFT] * Ab[m, k & ((1<<SHIFT)-1)]   (scale deferred)
// B[k,n] = Bt[n, k]   (pre-transposed, k-contiguous)
template<int SHIFT, int SEG_STEPS, bool ATOMIC>
__global__ __launch_bounds__(256, 2)
void kc_gemm(const ushort_t* __restrict__ Ab, const float* __restrict__ W,
             const ushort_t* __restrict__ Bt, float* __restrict__ C,
             int ldA, int ldB, int ldC, int ksteps)
{
    __shared__ ushort_t As[128 * BK];   // 32 KB, 16 chunks (of 8 bf16) per row
    __shared__ ushort_t Bs[128 * BK];   // XOR-swizzled: chunk c of row r at slot c^(r&15)

    const int t    = threadIdx.x;
    const int lane = t & 63;
    const int wv   = t >> 6;
    const int m0   = blockIdx.x * 128;
    const int n0   = blockIdx.y * 128;
    const int kbase = blockIdx.z * ksteps * BK;

    const int wm = (wv & 1) * 64;
    const int wn = (wv >> 1) * 64;
    const int fr = lane & 15;
    const int q  = lane >> 4;

    // staging map: deposit d = wv*8+c covers chunk-slots s = d*64+lane
    int srow[8], scol[8];
    #pragma unroll
    for (int c = 0; c < 8; ++c) {
        const int s = (wv * 8 + c) * 64 + lane;
        srow[c] = s >> 4;                               // LDS row
        scol[c] = ((s & 15) ^ (srow[c] & 15)) * 8;      // source k-offset (XOR swizzle)
    }

    f32x4 acc_out[4][4], acc_in[4][4];
    #pragma unroll
    for (int i = 0; i < 4; ++i)
        #pragma unroll
        for (int j = 0; j < 4; ++j)
            acc_out[i][j] = (f32x4){0.f, 0.f, 0.f, 0.f};

    const int nsegs = ksteps / SEG_STEPS;
    for (int seg = 0; seg < nsegs; ++seg) {
        const int segk = kbase + seg * SEG_STEPS * BK;
        const int nidx = segk >> SHIFT;

        #pragma unroll
        for (int i = 0; i < 4; ++i)
            #pragma unroll
            for (int j = 0; j < 4; ++j)
                acc_in[i][j] = (f32x4){0.f, 0.f, 0.f, 0.f};

        for (int ss = 0; ss < SEG_STEPS; ++ss) {
            const int k0 = segk + ss * BK;
            const int d0 = k0 & ((1 << SHIFT) - 1);

            __syncthreads();   // prior frag reads done before overwrite
            #pragma unroll
            for (int c = 0; c < 8; ++c) {
                glds16(Ab + (size_t)(m0 + srow[c]) * ldA + d0 + scol[c],
                       &As[(wv * 8 + c) * 512]);
                glds16(Bt + (size_t)(n0 + srow[c]) * ldB + k0 + scol[c],
                       &Bs[(wv * 8 + c) * 512]);
            }
            __syncthreads();   // drains vmcnt (global_load_lds) + lgkm

            #pragma unroll
            for (int kk = 0; kk < 4; ++kk) {
                frag_t a[4], b[4];
                const int csw = (q + 4 * kk) ^ fr;
                #pragma unroll
                for (int i = 0; i < 4; ++i) {
                    a[i] = *(const frag_t*)&As[((wm + 16 * i + fr) * 16 + csw) * 8];
                    b[i] = *(const frag_t*)&Bs[((wn + 16 * i + fr) * 16 + csw) * 8];
                }
                #pragma unroll
                for (int i = 0; i < 4; ++i)
                    #pragma unroll
                    for (int j = 0; j < 4; ++j)
                        acc_in[i][j] = __builtin_amdgcn_mfma_f32_16x16x32_bf16(
                                           a[i], b[j], acc_in[i][j], 0, 0, 0);
            }
        }

        // fold: acc_out += W[m, nidx] * acc_in   (W broadcast across lane&15)
        #pragma unroll
        for (int i = 0; i < 4; ++i) {
            #pragma unroll
            for (int r = 0; r < 4; ++r) {
                const int gm = m0 + wm + 16 * i + q * 4 + r;
                const float w = W[(size_t)gm * 64 + nidx];
                #pragma unroll
                for (int j = 0; j < 4; ++j)
                    acc_out[i][j][r] += w * acc_in[i][j][r];
            }
        }
    }

    // epilogue: C/D layout col=lane&15, row=q*4+reg
    #pragma unroll
    for (int i = 0; i < 4; ++i) {
        #pragma unroll
        for (int j = 0; j < 4; ++j) {
            #pragma unroll
            for (int r = 0; r < 4; ++r) {
                const int gm = m0 + wm + 16 * i + q * 4 + r;
                const int gn = n0 + wn + 16 * j + fr;
                if constexpr (ATOMIC)
                    atomicAdd(&C[(size_t)gm * ldC + gn], acc_out[i][j][r]);
                else
                    C[(size_t)gm * ldC + gn] = acc_out[i][j][r];
            }
        }
    }
}

extern "C" void kernel_launch(void* const* d_in, const int* in_sizes, int n_in,
                              void* d_out, int out_size, void* d_ws, size_t ws_size,
                              hipStream_t stream) {
    const float* x  = (const float*)d_in[0];   // [8192, 1024]
    const float* w1 = (const float*)d_in[1];   // [8192, 64]
    const float* w2 = (const float*)d_in[2];   // [8192, 64]
    const float* F  = (const float*)d_in[3];   // (65536, 128) k-major
    const float* Rk = (const float*)d_in[4];   // (8192, 1024) k-major
    float* out = (float*)d_out;                // [8192, 1024]

    char* ws = (char*)d_ws;
    float*    h    = (float*)ws;                         //  4 MB fp32
    ushort_t* buf1 = (ushort_t*)(ws + ((size_t)4  << 20)); // 16 MB: x_bf, then Rk_t
    ushort_t* F_t  = (ushort_t*)(ws + ((size_t)20 << 20)); // 16 MB
    ushort_t* h_bf = (ushort_t*)(ws + ((size_t)36 << 20)); //  2 MB
    // total footprint: 38 MB

    hipMemsetAsync(h, 0, (size_t)8192 * 128 * sizeof(float), stream);

    // prepasses for stage 1
    convert_bf<<<4096, 256, 0, stream>>>(x, buf1, 1048576);                 // x -> bf16
    transpose_bf<<<dim3(1024, 2), 256, 0, stream>>>(F, F_t, 65536, 128);    // F_t[128,65536]

    // Stage 1: M=8192 K=65536 N=128, split-K z=8 (8 n-segments per chunk)
    kc_gemm<10, 8, true><<<dim3(64, 1, 8), 256, 0, stream>>>(
        buf1, w1, F_t, h, 1024, 65536, 128, 64);

    // prepasses for stage 2 (Rk_t overlays buf1 — x_bf dead now)
    convert_bf<<<512, 256, 0, stream>>>(h, h_bf, 131072);                   // h -> bf16
    transpose_bf<<<dim3(128, 16), 256, 0, stream>>>(Rk, buf1, 8192, 1024);  // Rk_t[1024,8192]

    // Stage 2: M=8192 K=8192 N=1024, fold every step (segment = BK)
    kc_gemm<7, 1, false><<<dim3(64, 8, 1), 256, 0, stream>>>(
        h_bf, w2, buf1, out, 128, 8192, 1024, 64);
}